// Round 4
// baseline (232.869 us; speedup 1.0000x reference)
//
#include <hip/hip_runtime.h>
#include <hip/hip_bf16.h>
#include <stdint.h>

typedef unsigned short u16;
typedef __attribute__((ext_vector_type(8))) short bf16x8;
typedef __attribute__((ext_vector_type(4))) short bf16x4;
typedef __attribute__((ext_vector_type(4))) float f32x4;

__device__ __forceinline__ float bf2f(u16 u) {
    union { unsigned int i; float f; } v; v.i = ((unsigned int)u) << 16; return v.f;
}
__device__ __forceinline__ u16 f2bf(float f) {
    union { float f; unsigned int i; } v; v.f = f;
    unsigned int x = v.i;
    return (u16)((x + 0x7fffu + ((x >> 16) & 1u)) >> 16);
}
__device__ __forceinline__ unsigned fbits(float f) {
    union { float f; unsigned int i; } v; v.f = f; return v.i;
}
__device__ __forceinline__ void async16(const void* g, void* lds) {
    __builtin_amdgcn_global_load_lds((const __attribute__((address_space(1))) void*)g,
                                     (__attribute__((address_space(3))) void*)lds,
                                     16, 0, 0);
}

#define QSCALE 0.18033688f  /* 0.125 * log2(e): folded into Q so attn uses bare exp2 */

// ---------------------------------------------------------------------------
// prep: blocks 0..1023 transpose+convert the 4 weights (Wt[n][k]=bf16(W[k][n]));
//       blocks 1024..3071 convert tgt/memory fp32->bf16.
// ---------------------------------------------------------------------------
__global__ __launch_bounds__(256) void prep(
    const float* __restrict__ tgt, const float* __restrict__ mem,
    const float* __restrict__ Wq, const float* __restrict__ Wk,
    const float* __restrict__ Wv, const float* __restrict__ Wo,
    u16* __restrict__ Wt, u16* __restrict__ tgtb, u16* __restrict__ memb)
{
    __shared__ u16 tile[64][65];
    const int id = blockIdx.x;
    const int tid = threadIdx.x;
    if (id < 1024) {
        const int z = id >> 8;
        const float* in = (z == 0) ? Wq : (z == 1) ? Wk : (z == 2) ? Wv : Wo;
        u16* out = Wt + (size_t)z * 1048576;
        const int k0 = (id & 15) * 64, n0 = ((id >> 4) & 15) * 64;
        const int r = tid >> 2, c0 = (tid & 3) << 4;
#pragma unroll
        for (int i = 0; i < 4; ++i) {
            float4 v = *(const float4*)&in[(size_t)(k0 + r) * 1024 + n0 + c0 + i * 4];
            tile[c0 + i * 4 + 0][r] = f2bf(v.x);
            tile[c0 + i * 4 + 1][r] = f2bf(v.y);
            tile[c0 + i * 4 + 2][r] = f2bf(v.z);
            tile[c0 + i * 4 + 3][r] = f2bf(v.w);
        }
        __syncthreads();
#pragma unroll
        for (int i = 0; i < 2; ++i) {
            bf16x8 v;
#pragma unroll
            for (int j = 0; j < 8; ++j) v[j] = (short)tile[r][c0 + i * 8 + j];
            *(bf16x8*)&out[(size_t)(n0 + r) * 1024 + k0 + c0 + i * 8] = v;
        }
    } else {
        size_t i = ((size_t)(id - 1024) * 256 + tid) * 8;
        float4 a0 = *(const float4*)&tgt[i];
        float4 a1 = *(const float4*)&tgt[i + 4];
        float4 b0 = *(const float4*)&mem[i];
        float4 b1 = *(const float4*)&mem[i + 4];
        bf16x8 va, vb;
        va[0] = (short)f2bf(a0.x); va[1] = (short)f2bf(a0.y);
        va[2] = (short)f2bf(a0.z); va[3] = (short)f2bf(a0.w);
        va[4] = (short)f2bf(a1.x); va[5] = (short)f2bf(a1.y);
        va[6] = (short)f2bf(a1.z); va[7] = (short)f2bf(a1.w);
        vb[0] = (short)f2bf(b0.x); vb[1] = (short)f2bf(b0.y);
        vb[2] = (short)f2bf(b0.z); vb[3] = (short)f2bf(b0.w);
        vb[4] = (short)f2bf(b1.x); vb[5] = (short)f2bf(b1.y);
        vb[6] = (short)f2bf(b1.z); vb[7] = (short)f2bf(b1.w);
        *(bf16x8*)&tgtb[i] = va;
        *(bf16x8*)&memb[i] = vb;
    }
}

// ---------------------------------------------------------------------------
// QKV GEMM (R5 version): 128x128 tile, BK=32, single-buffered, XOR-swizzled.
// z==0: Q (scaled by QSCALE); z==1: K; z==2: V written transposed to Vt.
// ---------------------------------------------------------------------------
__global__ __launch_bounds__(256) void gemm_qkv(
    const u16* __restrict__ tgtb, const u16* __restrict__ memb,
    const u16* __restrict__ Wt,
    const float* __restrict__ bq, const float* __restrict__ bk, const float* __restrict__ bv,
    u16* __restrict__ Qb, u16* __restrict__ Kb, u16* __restrict__ Vtb)
{
    __shared__ __align__(16) u16 sA[128 * 32];
    __shared__ __align__(16) u16 sB[128 * 32];
    const int z = blockIdx.z;
    const u16* A = (z == 0) ? tgtb : memb;
    const u16* Bt = Wt + (size_t)z * 1048576;
    const float* bias = (z == 0) ? bq : (z == 1) ? bk : bv;

    const int tid = threadIdx.x;
    const int wave = tid >> 6, lane = tid & 63;
    const int quad = lane >> 4, l16 = lane & 15;
    const int m0 = blockIdx.x * 128, n0 = blockIdx.y * 128;
    const int wm = (wave & 1) * 64, wn = (wave >> 1) * 64;
    const int sw = (quad ^ ((l16 >> 1) & 3)) << 3;

    f32x4 acc[4][4] = {};

    for (int k0 = 0; k0 < 1024; k0 += 32) {
        __syncthreads();
#pragma unroll
        for (int r = 0; r < 2; ++r) {
            int c = tid + r * 256;
            int g = (c & 3) ^ ((c >> 3) & 3);
            const u16* gA = A + (size_t)(m0 + (c >> 2)) * 1024 + k0 + g * 8;
            async16(gA, (char*)sA + r * 4096 + wave * 1024);
            const u16* gB = Bt + (size_t)(n0 + (c >> 2)) * 1024 + k0 + g * 8;
            async16(gB, (char*)sB + r * 4096 + wave * 1024);
        }
        __syncthreads();
        bf16x8 af[4], bfr[4];
#pragma unroll
        for (int i = 0; i < 4; ++i) {
            af[i]  = *(const bf16x8*)&sA[(wm + i * 16 + l16) * 32 + sw];
            bfr[i] = *(const bf16x8*)&sB[(wn + i * 16 + l16) * 32 + sw];
        }
#pragma unroll
        for (int i = 0; i < 4; ++i)
#pragma unroll
            for (int j = 0; j < 4; ++j)
                acc[i][j] = __builtin_amdgcn_mfma_f32_16x16x32_bf16(af[i], bfr[j], acc[i][j], 0, 0, 0);
    }

    if (z == 2) {
#pragma unroll
        for (int j = 0; j < 4; ++j) {
            int n = n0 + wn + j * 16 + l16;
            float bb = bias[n];
            int d = n & 63;
#pragma unroll
            for (int i = 0; i < 4; ++i) {
                int mb = m0 + wm + i * 16 + quad * 4;
                int bh = (mb >> 11) * 16 + (n >> 6);
                bf16x4 pk;
#pragma unroll
                for (int r = 0; r < 4; ++r) pk[r] = (short)f2bf(acc[i][j][r] + bb);
                *(bf16x4*)&Vtb[(size_t)bh * 131072 + (size_t)d * 2048 + (mb & 2047)] = pk;
            }
        }
    } else {
        u16* C = (z == 0) ? Qb : Kb;
        const float scl = (z == 0) ? QSCALE : 1.0f;
#pragma unroll
        for (int j = 0; j < 4; ++j) {
            int n = n0 + wn + j * 16 + l16;
            float bb = bias[n];
#pragma unroll
            for (int i = 0; i < 4; ++i) {
                int mb = m0 + wm + i * 16 + quad * 4;
#pragma unroll
                for (int r = 0; r < 4; ++r)
                    C[(size_t)(mb + r) * 1024 + n] = f2bf((acc[i][j][r] + bb) * scl);
            }
        }
    }
}

// ---------------------------------------------------------------------------
// Output GEMM (R5 version): 64x128 tile, single-buffered, fp32 out.
// ---------------------------------------------------------------------------
__global__ __launch_bounds__(256) void gemm_out(
    const u16* __restrict__ A, const u16* __restrict__ Bt,
    const float* __restrict__ bias, float* __restrict__ C)
{
    __shared__ __align__(16) u16 sA[64 * 32];
    __shared__ __align__(16) u16 sB[128 * 32];
    const int tid = threadIdx.x;
    const int wave = tid >> 6, lane = tid & 63;
    const int quad = lane >> 4, l16 = lane & 15;
    const int m0 = blockIdx.x * 64, n0 = blockIdx.y * 128;
    const int wm = (wave & 1) * 32, wn = (wave >> 1) * 64;
    const int sw = (quad ^ ((l16 >> 1) & 3)) << 3;
    f32x4 acc[2][4] = {};

    for (int k0 = 0; k0 < 1024; k0 += 32) {
        __syncthreads();
        {
            int c = tid;
            int g = (c & 3) ^ ((c >> 3) & 3);
            const u16* gA = A + (size_t)(m0 + (c >> 2)) * 1024 + k0 + g * 8;
            async16(gA, (char*)sA + wave * 1024);
        }
#pragma unroll
        for (int r = 0; r < 2; ++r) {
            int c = tid + r * 256;
            int g = (c & 3) ^ ((c >> 3) & 3);
            const u16* gB = Bt + (size_t)(n0 + (c >> 2)) * 1024 + k0 + g * 8;
            async16(gB, (char*)sB + r * 4096 + wave * 1024);
        }
        __syncthreads();
        bf16x8 af[2], bfr[4];
#pragma unroll
        for (int i = 0; i < 2; ++i)
            af[i] = *(const bf16x8*)&sA[(wm + i * 16 + l16) * 32 + sw];
#pragma unroll
        for (int j = 0; j < 4; ++j)
            bfr[j] = *(const bf16x8*)&sB[(wn + j * 16 + l16) * 32 + sw];
#pragma unroll
        for (int i = 0; i < 2; ++i)
#pragma unroll
            for (int j = 0; j < 4; ++j)
                acc[i][j] = __builtin_amdgcn_mfma_f32_16x16x32_bf16(af[i], bfr[j], acc[i][j], 0, 0, 0);
    }
#pragma unroll
    for (int j = 0; j < 4; ++j) {
        int n = n0 + wn + j * 16 + l16;
        float bb = bias[n];
#pragma unroll
        for (int i = 0; i < 2; ++i) {
            int mb = m0 + wm + i * 16 + quad * 4;
#pragma unroll
            for (int r = 0; r < 4; ++r)
                C[(size_t)(mb + r) * 1024 + n] = acc[i][j][r] + bb;
        }
    }
}

// ---------------------------------------------------------------------------
// Attention v9 (split-KV): R3's proven per-wave math (4 waves x 32 q rows,
// groups A/B, register-hoisted fragments, fbits+perm pack, setprio), but
// grid doubled to 1024 blocks: block half h processes kv tiles
// [h*16, h*16+16) and writes UNNORMALIZED partial O^T (f32) + partial
// rowsums. R3 counters showed grid-limited occupancy (18%, 2 waves/SIMD,
// 76% issue-busy) -- split-kv doubles waves/SIMD to 4 with the same
// 32q/wave LDS reuse. A combine kernel sums partials and normalizes.
// Partial layout: O[bh][qloc][d] f32 (16 MB per half).
// ---------------------------------------------------------------------------
__global__ __launch_bounds__(256, 2) void attn_kernel(
    const u16* __restrict__ Q,   // (B*T) x 1024, pre-scaled by QSCALE
    const u16* __restrict__ K,   // (B*T) x 1024
    const u16* __restrict__ Vt,  // (B*H) x 64 x 2048
    float* __restrict__ O0, float* __restrict__ O1,
    float* __restrict__ R0, float* __restrict__ R1)
{
    __shared__ __align__(16) u16 sK[2][4096];   // [buf][64kv x 64d swizzled]
    __shared__ __align__(16) u16 sV[2][4096];   // [buf][64d x 64kv swizzled]

    const int tid = threadIdx.x;
    const int wave = tid >> 6, lane = tid & 63;
    const int quad = lane >> 4, l16 = lane & 15;

    const int bidx = blockIdx.x;
    const int half = bidx >> 9;                          // kv half: 0 or 1
    const int b9 = bidx & 511;
    const int bh = (b9 & 7) * 4 + ((b9 >> 3) & 3);       // XCD swizzle
    const int qt = b9 >> 5;                              // 0..15 (128-q tiles)
    const int b = bh >> 4, h = bh & 15;
    const size_t qrow0 = (size_t)b * 2048 + qt * 128;
    const int st = ((qt << 1) | (bh & 1)) & 15;          // kv stagger in half
    const int tbase = half * 16;                         // first tile of half

    // Q B-frags: wave owns q rows [wave*32, wave*32+32); group A = first 16,
    // group B = second 16. n=q=l16, k=d.
    const size_t qrowA = qrow0 + wave * 32 + l16;
    const size_t qrowB = qrowA + 16;
    bf16x8 qA0 = *(const bf16x8*)&Q[qrowA * 1024 + h * 64 + quad * 8];
    bf16x8 qA1 = *(const bf16x8*)&Q[qrowA * 1024 + h * 64 + 32 + quad * 8];
    bf16x8 qB0 = *(const bf16x8*)&Q[qrowB * 1024 + h * 64 + quad * 8];
    bf16x8 qB1 = *(const bf16x8*)&Q[qrowB * 1024 + h * 64 + 32 + quad * 8];

    f32x4 oA[4] = {}, oB[4] = {};   // O^T [d=mt*16+quad*4+r][q=l16]
    float rowA = 0.0f, rowB = 0.0f;

    const u16* Kbase = K + (size_t)b * 2048 * 1024 + h * 64;
    const u16* Vbase = Vt + (size_t)bh * 131072;

    // LDS read offsets (u16 elements), XOR-swizzled 16B-chunk addressing.
    const int x7 = l16 & 7;
    int koff[2], voff[4];
#pragma unroll
    for (int kf = 0; kf < 2; ++kf)
        koff[kf] = (l16 * 8 + ((kf * 4 + quad) ^ x7)) * 8;
#pragma unroll
    for (int ks = 0; ks < 4; ++ks)
        voff[ks] = (l16 * 8 + ((ks * 2 + (quad >> 1)) ^ x7)) * 8 + (quad & 1) * 4;

    // staging: 256 threads cover a full 8KB tile in TWO async16 per operand.
#define STAGE1(kv0, buf, r)                                                   \
    {                                                                         \
        int c = tid + (r) * 256;                                              \
        int srow = c >> 3;                                                    \
        int g = (c & 7) ^ (srow & 7);                                         \
        async16(Kbase + (size_t)((kv0) + srow) * 1024 + g * 8,                \
                (char*)&sK[buf][0] + (r) * 4096 + wave * 1024);               \
        async16(Vbase + (size_t)srow * 2048 + (kv0) + g * 8,                  \
                (char*)&sV[buf][0] + (r) * 4096 + wave * 1024);               \
    }
#define STAGE(kv0, buf) STAGE1(kv0, buf, 0) STAGE1(kv0, buf, 1)

    STAGE((tbase + st) * 64, 0);

    for (int i = 0; i < 16; ++i) {
        __syncthreads();   // drains stage(i); buf[(i+1)&1] is free
        if (i < 15) {
            int kvn = (tbase + ((st + i + 1) & 15)) * 64;
            STAGE(kvn, (i + 1) & 1);
        }
        const u16* kb = &sK[i & 1][0];
        const u16* vb = &sV[i & 1][0];

        // Hoist the whole tile's fragments into registers (statically
        // indexed under full unroll -> stays in VGPRs).
        bf16x8 kfr[4][2];
        bf16x4 vfr[4][4];   // [mt][ks]
#pragma unroll
        for (int ks = 0; ks < 4; ++ks) {
            kfr[ks][0] = *(const bf16x8*)&kb[ks * 1024 + koff[0]];
            kfr[ks][1] = *(const bf16x8*)&kb[ks * 1024 + koff[1]];
        }
#pragma unroll
        for (int mt = 0; mt < 4; ++mt)
#pragma unroll
            for (int ks = 0; ks < 4; ++ks)
                vfr[mt][ks] = *(const bf16x4*)&vb[mt * 1024 + voff[ks]];

        __builtin_amdgcn_s_setprio(1);
#pragma unroll
        for (int ks = 0; ks < 4; ++ks) {
            f32x4 sA = {0.f, 0.f, 0.f, 0.f};
            f32x4 sB = {0.f, 0.f, 0.f, 0.f};
            sA = __builtin_amdgcn_mfma_f32_16x16x32_bf16(kfr[ks][0], qA0, sA, 0, 0, 0);
            sB = __builtin_amdgcn_mfma_f32_16x16x32_bf16(kfr[ks][0], qB0, sB, 0, 0, 0);
            sA = __builtin_amdgcn_mfma_f32_16x16x32_bf16(kfr[ks][1], qA1, sA, 0, 0, 0);
            sB = __builtin_amdgcn_mfma_f32_16x16x32_bf16(kfr[ks][1], qB1, sB, 0, 0, 0);
            float a0 = __builtin_amdgcn_exp2f(sA[0]);
            float a1 = __builtin_amdgcn_exp2f(sA[1]);
            float a2 = __builtin_amdgcn_exp2f(sA[2]);
            float a3 = __builtin_amdgcn_exp2f(sA[3]);
            float b0 = __builtin_amdgcn_exp2f(sB[0]);
            float b1 = __builtin_amdgcn_exp2f(sB[1]);
            float b2 = __builtin_amdgcn_exp2f(sB[2]);
            float b3 = __builtin_amdgcn_exp2f(sB[3]);
            rowA += (a0 + a1) + (a2 + a3);
            rowB += (b0 + b1) + (b2 + b3);
            unsigned loA = __builtin_amdgcn_perm(fbits(a1) + 0x8000u, fbits(a0) + 0x8000u, 0x07060302u);
            unsigned hiA = __builtin_amdgcn_perm(fbits(a3) + 0x8000u, fbits(a2) + 0x8000u, 0x07060302u);
            unsigned loB = __builtin_amdgcn_perm(fbits(b1) + 0x8000u, fbits(b0) + 0x8000u, 0x07060302u);
            unsigned hiB = __builtin_amdgcn_perm(fbits(b3) + 0x8000u, fbits(b2) + 0x8000u, 0x07060302u);
            union { unsigned u[2]; bf16x4 v; } pA, pB;
            pA.u[0] = loA; pA.u[1] = hiA;
            pB.u[0] = loB; pB.u[1] = hiB;
#pragma unroll
            for (int mt = 0; mt < 4; ++mt) {
                oA[mt] = __builtin_amdgcn_mfma_f32_16x16x16bf16_1k(vfr[mt][ks], pA.v, oA[mt], 0, 0, 0);
                oB[mt] = __builtin_amdgcn_mfma_f32_16x16x16bf16_1k(vfr[mt][ks], pB.v, oB[mt], 0, 0, 0);
            }
        }
        __builtin_amdgcn_s_setprio(0);
    }
#undef STAGE
#undef STAGE1

    // rowsum butterfly over quads: every lane gets half-total for q=l16
    rowA += __shfl_xor(rowA, 16, 64);
    rowA += __shfl_xor(rowA, 32, 64);
    rowB += __shfl_xor(rowB, 16, 64);
    rowB += __shfl_xor(rowB, 32, 64);

    // write UNNORMALIZED partials: O[bh][qloc][d] f32, rowsum R[bh][qloc]
    float* Op = half ? O1 : O0;
    float* Rp = half ? R1 : R0;
    const int qlocA = qt * 128 + wave * 32 + l16;
    const size_t obaseA = ((size_t)bh * 2048 + qlocA) * 64;
    const size_t obaseB = obaseA + 16 * 64;
#pragma unroll
    for (int mt = 0; mt < 4; ++mt) {
        *(f32x4*)&Op[obaseA + mt * 16 + quad * 4] = oA[mt];
        *(f32x4*)&Op[obaseB + mt * 16 + quad * 4] = oB[mt];
    }
    if (quad == 0) {
        Rp[bh * 2048 + qlocA] = rowA;
        Rp[bh * 2048 + qlocA + 16] = rowB;
    }
}

// ---------------------------------------------------------------------------
// combine: Y[b,t,h*64+d] = (O0+O1)[bh][qloc][d] / (R0+R1)[bh][qloc], bf16.
// 1M float4-chunks; 1024 blocks x 256 threads x 4 iters, fully coalesced.
// ---------------------------------------------------------------------------
__global__ __launch_bounds__(256) void combine(
    const float* __restrict__ O0, const float* __restrict__ O1,
    const float* __restrict__ R0, const float* __restrict__ R1,
    u16* __restrict__ Y)
{
    const int t0 = blockIdx.x * 256 + threadIdx.x;
#pragma unroll
    for (int it = 0; it < 4; ++it) {
        int g = t0 + it * 262144;
        int m = g >> 4;                 // row: bh*2048 + qloc
        int dq = (g & 15) * 4;          // d offset
        int bh = m >> 11, qloc = m & 2047;
        int b = bh >> 4, h = bh & 15;
        f32x4 a = *(const f32x4*)&O0[(size_t)m * 64 + dq];
        f32x4 c = *(const f32x4*)&O1[(size_t)m * 64 + dq];
        float inv = 1.0f / (R0[m] + R1[m]);
        bf16x4 y;
#pragma unroll
        for (int r = 0; r < 4; ++r) y[r] = (short)f2bf((a[r] + c[r]) * inv);
        *(bf16x4*)&Y[((size_t)b * 2048 + qloc) * 1024 + h * 64 + dq] = y;
    }
}

// ---------------------------------------------------------------------------
extern "C" void kernel_launch(void* const* d_in, const int* in_sizes, int n_in,
                              void* d_out, int out_size, void* d_ws, size_t ws_size,
                              hipStream_t stream) {
    const float* tgt = (const float*)d_in[0];
    const float* mem = (const float*)d_in[1];
    const float* Wq  = (const float*)d_in[2];
    const float* bq  = (const float*)d_in[3];
    const float* Wk  = (const float*)d_in[4];
    const float* bk  = (const float*)d_in[5];
    const float* Wv  = (const float*)d_in[6];
    const float* bv  = (const float*)d_in[7];
    const float* Wo  = (const float*)d_in[8];
    const float* bo  = (const float*)d_in[9];

    u16* ws = (u16*)d_ws;
    const size_t SZ = 4194304;          // elements per 4096x1024 bf16 buffer
    u16* Wt   = ws;                     // 4 x 1024x1024 bf16, occupies [0,SZ)
    u16* tgtb = ws + 4 * SZ;
    u16* memb = tgtb + SZ;
    u16* Qb   = memb + SZ;
    u16* Kb   = Qb + SZ;
    u16* Vtb  = Kb + SZ;                // 32 x 64 x 2048
    u16* Yb   = Vtb + SZ;
    float* out = (float*)d_out;

    // split-KV partial buffers, carved from dead/unused ws regions:
    //  O0 = [SZ,3SZ) (never-used gap after Wt), O1 = [3SZ,5SZ) (gap + dead
    //  tgtb), R0/R1 in dead memb. All dead during/after attn.
    float* O0 = (float*)(ws + SZ);
    float* O1 = (float*)(ws + 3 * SZ);
    float* R0 = (float*)(ws + 5 * SZ);
    float* R1 = R0 + 65536;

    prep<<<dim3(3072), 256, 0, stream>>>(tgt, mem, Wq, Wk, Wv, Wo, Wt, tgtb, memb);
    gemm_qkv<<<dim3(32, 8, 3), 256, 0, stream>>>(tgtb, memb, Wt, bq, bk, bv, Qb, Kb, Vtb);
    attn_kernel<<<dim3(1024), 256, 0, stream>>>(Qb, Kb, Vtb, O0, O1, R0, R1);
    combine<<<dim3(1024), 256, 0, stream>>>(O0, O1, R0, R1, Yb);
    gemm_out<<<dim3(64, 8), 256, 0, stream>>>(Yb, Wt + 3 * (size_t)1048576, bo, out);
}

// Round 5
// 213.193 us; speedup vs baseline: 1.0923x; 1.0923x over previous
//
#include <hip/hip_runtime.h>
#include <hip/hip_bf16.h>
#include <stdint.h>

typedef unsigned short u16;
typedef __attribute__((ext_vector_type(8))) short bf16x8;
typedef __attribute__((ext_vector_type(4))) short bf16x4;
typedef __attribute__((ext_vector_type(4))) float f32x4;

__device__ __forceinline__ float bf2f(u16 u) {
    union { unsigned int i; float f; } v; v.i = ((unsigned int)u) << 16; return v.f;
}
__device__ __forceinline__ u16 f2bf(float f) {
    union { float f; unsigned int i; } v; v.f = f;
    unsigned int x = v.i;
    return (u16)((x + 0x7fffu + ((x >> 16) & 1u)) >> 16);
}
__device__ __forceinline__ unsigned fbits(float f) {
    union { float f; unsigned int i; } v; v.f = f; return v.i;
}
__device__ __forceinline__ void async16(const void* g, void* lds) {
    __builtin_amdgcn_global_load_lds((const __attribute__((address_space(1))) void*)g,
                                     (__attribute__((address_space(3))) void*)lds,
                                     16, 0, 0);
}

#define QSCALE 0.18033688f  /* 0.125 * log2(e): folded into Q so attn uses bare exp2 */

// ---------------------------------------------------------------------------
// prep: blocks 0..1023 transpose+convert the 4 weights (Wt[n][k]=bf16(W[k][n]));
//       blocks 1024..3071 convert tgt/memory fp32->bf16.
// ---------------------------------------------------------------------------
__global__ __launch_bounds__(256) void prep(
    const float* __restrict__ tgt, const float* __restrict__ mem,
    const float* __restrict__ Wq, const float* __restrict__ Wk,
    const float* __restrict__ Wv, const float* __restrict__ Wo,
    u16* __restrict__ Wt, u16* __restrict__ tgtb, u16* __restrict__ memb)
{
    __shared__ u16 tile[64][65];
    const int id = blockIdx.x;
    const int tid = threadIdx.x;
    if (id < 1024) {
        const int z = id >> 8;
        const float* in = (z == 0) ? Wq : (z == 1) ? Wk : (z == 2) ? Wv : Wo;
        u16* out = Wt + (size_t)z * 1048576;
        const int k0 = (id & 15) * 64, n0 = ((id >> 4) & 15) * 64;
        const int r = tid >> 2, c0 = (tid & 3) << 4;
#pragma unroll
        for (int i = 0; i < 4; ++i) {
            float4 v = *(const float4*)&in[(size_t)(k0 + r) * 1024 + n0 + c0 + i * 4];
            tile[c0 + i * 4 + 0][r] = f2bf(v.x);
            tile[c0 + i * 4 + 1][r] = f2bf(v.y);
            tile[c0 + i * 4 + 2][r] = f2bf(v.z);
            tile[c0 + i * 4 + 3][r] = f2bf(v.w);
        }
        __syncthreads();
#pragma unroll
        for (int i = 0; i < 2; ++i) {
            bf16x8 v;
#pragma unroll
            for (int j = 0; j < 8; ++j) v[j] = (short)tile[r][c0 + i * 8 + j];
            *(bf16x8*)&out[(size_t)(n0 + r) * 1024 + k0 + c0 + i * 8] = v;
        }
    } else {
        size_t i = ((size_t)(id - 1024) * 256 + tid) * 8;
        float4 a0 = *(const float4*)&tgt[i];
        float4 a1 = *(const float4*)&tgt[i + 4];
        float4 b0 = *(const float4*)&mem[i];
        float4 b1 = *(const float4*)&mem[i + 4];
        bf16x8 va, vb;
        va[0] = (short)f2bf(a0.x); va[1] = (short)f2bf(a0.y);
        va[2] = (short)f2bf(a0.z); va[3] = (short)f2bf(a0.w);
        va[4] = (short)f2bf(a1.x); va[5] = (short)f2bf(a1.y);
        va[6] = (short)f2bf(a1.z); va[7] = (short)f2bf(a1.w);
        vb[0] = (short)f2bf(b0.x); vb[1] = (short)f2bf(b0.y);
        vb[2] = (short)f2bf(b0.z); vb[3] = (short)f2bf(b0.w);
        vb[4] = (short)f2bf(b1.x); vb[5] = (short)f2bf(b1.y);
        vb[6] = (short)f2bf(b1.z); vb[7] = (short)f2bf(b1.w);
        *(bf16x8*)&tgtb[i] = va;
        *(bf16x8*)&memb[i] = vb;
    }
}

// ---------------------------------------------------------------------------
// QKV GEMM v2: 128x128 tile, BK=64 (16 K-steps, half the barrier drains of
// BK=32), single-buffered, XOR-swizzled (8 chunks/row, chunk ^= row&7).
// z==0: Q (scaled by QSCALE); z==1: K; z==2: V written transposed to Vt.
// ---------------------------------------------------------------------------
__global__ __launch_bounds__(256) void gemm_qkv(
    const u16* __restrict__ tgtb, const u16* __restrict__ memb,
    const u16* __restrict__ Wt,
    const float* __restrict__ bq, const float* __restrict__ bk, const float* __restrict__ bv,
    u16* __restrict__ Qb, u16* __restrict__ Kb, u16* __restrict__ Vtb)
{
    __shared__ __align__(16) u16 sA[128 * 64];   // 16 KB
    __shared__ __align__(16) u16 sB[128 * 64];   // 16 KB
    const int z = blockIdx.z;
    const u16* A = (z == 0) ? tgtb : memb;
    const u16* Bt = Wt + (size_t)z * 1048576;
    const float* bias = (z == 0) ? bq : (z == 1) ? bk : bv;

    const int tid = threadIdx.x;
    const int wave = tid >> 6, lane = tid & 63;
    const int quad = lane >> 4, l16 = lane & 15;
    const int m0 = blockIdx.x * 128, n0 = blockIdx.y * 128;
    const int wm = (wave & 1) * 64, wn = (wave >> 1) * 64;
    const int x7 = l16 & 7;

    f32x4 acc[4][4] = {};

    for (int k0 = 0; k0 < 1024; k0 += 64) {
        __syncthreads();
#pragma unroll
        for (int r = 0; r < 4; ++r) {
            int c = tid + r * 256;
            int srow = c >> 3;
            int g = (c & 7) ^ (srow & 7);
            const u16* gA = A + (size_t)(m0 + srow) * 1024 + k0 + g * 8;
            async16(gA, (char*)sA + r * 4096 + wave * 1024);
            const u16* gB = Bt + (size_t)(n0 + srow) * 1024 + k0 + g * 8;
            async16(gB, (char*)sB + r * 4096 + wave * 1024);
        }
        __syncthreads();
#pragma unroll
        for (int h = 0; h < 2; ++h) {
            bf16x8 af[4], bfr[4];
#pragma unroll
            for (int i = 0; i < 4; ++i) {
                af[i]  = *(const bf16x8*)&sA[(wm + i * 16 + l16) * 64 + (((h * 4 + quad) ^ x7) * 8)];
                bfr[i] = *(const bf16x8*)&sB[(wn + i * 16 + l16) * 64 + (((h * 4 + quad) ^ x7) * 8)];
            }
#pragma unroll
            for (int i = 0; i < 4; ++i)
#pragma unroll
                for (int j = 0; j < 4; ++j)
                    acc[i][j] = __builtin_amdgcn_mfma_f32_16x16x32_bf16(af[i], bfr[j], acc[i][j], 0, 0, 0);
        }
    }

    if (z == 2) {
#pragma unroll
        for (int j = 0; j < 4; ++j) {
            int n = n0 + wn + j * 16 + l16;
            float bb = bias[n];
            int d = n & 63;
#pragma unroll
            for (int i = 0; i < 4; ++i) {
                int mb = m0 + wm + i * 16 + quad * 4;
                int bh = (mb >> 11) * 16 + (n >> 6);
                bf16x4 pk;
#pragma unroll
                for (int r = 0; r < 4; ++r) pk[r] = (short)f2bf(acc[i][j][r] + bb);
                *(bf16x4*)&Vtb[(size_t)bh * 131072 + (size_t)d * 2048 + (mb & 2047)] = pk;
            }
        }
    } else {
        u16* C = (z == 0) ? Qb : Kb;
        const float scl = (z == 0) ? QSCALE : 1.0f;
#pragma unroll
        for (int j = 0; j < 4; ++j) {
            int n = n0 + wn + j * 16 + l16;
            float bb = bias[n];
#pragma unroll
            for (int i = 0; i < 4; ++i) {
                int mb = m0 + wm + i * 16 + quad * 4;
#pragma unroll
                for (int r = 0; r < 4; ++r)
                    C[(size_t)(mb + r) * 1024 + n] = f2bf((acc[i][j][r] + bb) * scl);
            }
        }
    }
}

// ---------------------------------------------------------------------------
// Output GEMM v2: 64x128 tile, BK=64 (16 K-steps), single-buffered, fp32 out.
// ---------------------------------------------------------------------------
__global__ __launch_bounds__(256) void gemm_out(
    const u16* __restrict__ A, const u16* __restrict__ Bt,
    const float* __restrict__ bias, float* __restrict__ C)
{
    __shared__ __align__(16) u16 sA[64 * 64];    // 8 KB
    __shared__ __align__(16) u16 sB[128 * 64];   // 16 KB
    const int tid = threadIdx.x;
    const int wave = tid >> 6, lane = tid & 63;
    const int quad = lane >> 4, l16 = lane & 15;
    const int m0 = blockIdx.x * 64, n0 = blockIdx.y * 128;
    const int wm = (wave & 1) * 32, wn = (wave >> 1) * 64;
    const int x7 = l16 & 7;
    f32x4 acc[2][4] = {};

    for (int k0 = 0; k0 < 1024; k0 += 64) {
        __syncthreads();
#pragma unroll
        for (int r = 0; r < 2; ++r) {
            int c = tid + r * 256;
            int srow = c >> 3;
            int g = (c & 7) ^ (srow & 7);
            const u16* gA = A + (size_t)(m0 + srow) * 1024 + k0 + g * 8;
            async16(gA, (char*)sA + r * 4096 + wave * 1024);
        }
#pragma unroll
        for (int r = 0; r < 4; ++r) {
            int c = tid + r * 256;
            int srow = c >> 3;
            int g = (c & 7) ^ (srow & 7);
            const u16* gB = Bt + (size_t)(n0 + srow) * 1024 + k0 + g * 8;
            async16(gB, (char*)sB + r * 4096 + wave * 1024);
        }
        __syncthreads();
#pragma unroll
        for (int h = 0; h < 2; ++h) {
            bf16x8 af[2], bfr[4];
#pragma unroll
            for (int i = 0; i < 2; ++i)
                af[i] = *(const bf16x8*)&sA[(wm + i * 16 + l16) * 64 + (((h * 4 + quad) ^ x7) * 8)];
#pragma unroll
            for (int j = 0; j < 4; ++j)
                bfr[j] = *(const bf16x8*)&sB[(wn + j * 16 + l16) * 64 + (((h * 4 + quad) ^ x7) * 8)];
#pragma unroll
            for (int i = 0; i < 2; ++i)
#pragma unroll
                for (int j = 0; j < 4; ++j)
                    acc[i][j] = __builtin_amdgcn_mfma_f32_16x16x32_bf16(af[i], bfr[j], acc[i][j], 0, 0, 0);
        }
    }
#pragma unroll
    for (int j = 0; j < 4; ++j) {
        int n = n0 + wn + j * 16 + l16;
        float bb = bias[n];
#pragma unroll
        for (int i = 0; i < 2; ++i) {
            int mb = m0 + wm + i * 16 + quad * 4;
#pragma unroll
            for (int r = 0; r < 4; ++r)
                C[(size_t)(mb + r) * 1024 + n] = acc[i][j][r] + bb;
        }
    }
}

// ---------------------------------------------------------------------------
// Attention v8 (R3 proven version, reverted from split-KV): 4 waves x 32 q
// rows (two 16-q groups A/B per wave), full kv range per block, double-
// buffered 64-kv tiles, one barrier per tile, register-hoisted fragments,
// fbits+perm pack, setprio around compute. 54.6 us measured.
// ---------------------------------------------------------------------------
__global__ __launch_bounds__(256, 2) void attn_kernel(
    const u16* __restrict__ Q,   // (B*T) x 1024, pre-scaled by QSCALE
    const u16* __restrict__ K,   // (B*T) x 1024
    const u16* __restrict__ Vt,  // (B*H) x 64 x 2048
    u16* __restrict__ Y)         // (B*T) x 1024
{
    __shared__ __align__(16) u16 sK[2][4096];   // [buf][64kv x 64d swizzled]
    __shared__ __align__(16) u16 sV[2][4096];   // [buf][64d x 64kv swizzled]

    const int tid = threadIdx.x;
    const int wave = tid >> 6, lane = tid & 63;
    const int quad = lane >> 4, l16 = lane & 15;

    const int bidx = blockIdx.x;
    const int bh = (bidx & 7) * 4 + ((bidx >> 3) & 3);   // XCD swizzle
    const int qt = bidx >> 5;            // 0..15 (128-q tiles)
    const int b = bh >> 4, h = bh & 15;
    const size_t qrow0 = (size_t)b * 2048 + qt * 128;
    const int st = ((qt << 1) | (bh & 1)) & 31;          // kv stagger

    const size_t qrowA = qrow0 + wave * 32 + l16;
    const size_t qrowB = qrowA + 16;
    bf16x8 qA0 = *(const bf16x8*)&Q[qrowA * 1024 + h * 64 + quad * 8];
    bf16x8 qA1 = *(const bf16x8*)&Q[qrowA * 1024 + h * 64 + 32 + quad * 8];
    bf16x8 qB0 = *(const bf16x8*)&Q[qrowB * 1024 + h * 64 + quad * 8];
    bf16x8 qB1 = *(const bf16x8*)&Q[qrowB * 1024 + h * 64 + 32 + quad * 8];

    f32x4 oA[4] = {}, oB[4] = {};   // O^T [d=mt*16+quad*4+r][q=l16]
    float rowA = 0.0f, rowB = 0.0f;

    const u16* Kbase = K + (size_t)b * 2048 * 1024 + h * 64;
    const u16* Vbase = Vt + (size_t)bh * 131072;

    const int x7 = l16 & 7;
    int koff[2], voff[4];
#pragma unroll
    for (int kf = 0; kf < 2; ++kf)
        koff[kf] = (l16 * 8 + ((kf * 4 + quad) ^ x7)) * 8;
#pragma unroll
    for (int ks = 0; ks < 4; ++ks)
        voff[ks] = (l16 * 8 + ((ks * 2 + (quad >> 1)) ^ x7)) * 8 + (quad & 1) * 4;

#define STAGE1(kv0, buf, r)                                                   \
    {                                                                         \
        int c = tid + (r) * 256;                                              \
        int srow = c >> 3;                                                    \
        int g = (c & 7) ^ (srow & 7);                                         \
        async16(Kbase + (size_t)((kv0) + srow) * 1024 + g * 8,                \
                (char*)&sK[buf][0] + (r) * 4096 + wave * 1024);               \
        async16(Vbase + (size_t)srow * 2048 + (kv0) + g * 8,                  \
                (char*)&sV[buf][0] + (r) * 4096 + wave * 1024);               \
    }
#define STAGE(kv0, buf) STAGE1(kv0, buf, 0) STAGE1(kv0, buf, 1)

    STAGE(st * 64, 0);

    for (int i = 0; i < 32; ++i) {
        __syncthreads();   // drains stage(i); buf[(i+1)&1] is free
        if (i < 31) {
            int kvn = ((st + i + 1) & 31) * 64;
            STAGE(kvn, (i + 1) & 1);
        }
        const u16* kb = &sK[i & 1][0];
        const u16* vb = &sV[i & 1][0];

        bf16x8 kfr[4][2];
        bf16x4 vfr[4][4];   // [mt][ks]
#pragma unroll
        for (int ks = 0; ks < 4; ++ks) {
            kfr[ks][0] = *(const bf16x8*)&kb[ks * 1024 + koff[0]];
            kfr[ks][1] = *(const bf16x8*)&kb[ks * 1024 + koff[1]];
        }
#pragma unroll
        for (int mt = 0; mt < 4; ++mt)
#pragma unroll
            for (int ks = 0; ks < 4; ++ks)
                vfr[mt][ks] = *(const bf16x4*)&vb[mt * 1024 + voff[ks]];

        __builtin_amdgcn_s_setprio(1);
#pragma unroll
        for (int ks = 0; ks < 4; ++ks) {
            f32x4 sA = {0.f, 0.f, 0.f, 0.f};
            f32x4 sB = {0.f, 0.f, 0.f, 0.f};
            sA = __builtin_amdgcn_mfma_f32_16x16x32_bf16(kfr[ks][0], qA0, sA, 0, 0, 0);
            sB = __builtin_amdgcn_mfma_f32_16x16x32_bf16(kfr[ks][0], qB0, sB, 0, 0, 0);
            sA = __builtin_amdgcn_mfma_f32_16x16x32_bf16(kfr[ks][1], qA1, sA, 0, 0, 0);
            sB = __builtin_amdgcn_mfma_f32_16x16x32_bf16(kfr[ks][1], qB1, sB, 0, 0, 0);
            float a0 = __builtin_amdgcn_exp2f(sA[0]);
            float a1 = __builtin_amdgcn_exp2f(sA[1]);
            float a2 = __builtin_amdgcn_exp2f(sA[2]);
            float a3 = __builtin_amdgcn_exp2f(sA[3]);
            float b0 = __builtin_amdgcn_exp2f(sB[0]);
            float b1 = __builtin_amdgcn_exp2f(sB[1]);
            float b2 = __builtin_amdgcn_exp2f(sB[2]);
            float b3 = __builtin_amdgcn_exp2f(sB[3]);
            rowA += (a0 + a1) + (a2 + a3);
            rowB += (b0 + b1) + (b2 + b3);
            unsigned loA = __builtin_amdgcn_perm(fbits(a1) + 0x8000u, fbits(a0) + 0x8000u, 0x07060302u);
            unsigned hiA = __builtin_amdgcn_perm(fbits(a3) + 0x8000u, fbits(a2) + 0x8000u, 0x07060302u);
            unsigned loB = __builtin_amdgcn_perm(fbits(b1) + 0x8000u, fbits(b0) + 0x8000u, 0x07060302u);
            unsigned hiB = __builtin_amdgcn_perm(fbits(b3) + 0x8000u, fbits(b2) + 0x8000u, 0x07060302u);
            union { unsigned u[2]; bf16x4 v; } pA, pB;
            pA.u[0] = loA; pA.u[1] = hiA;
            pB.u[0] = loB; pB.u[1] = hiB;
#pragma unroll
            for (int mt = 0; mt < 4; ++mt) {
                oA[mt] = __builtin_amdgcn_mfma_f32_16x16x16bf16_1k(vfr[mt][ks], pA.v, oA[mt], 0, 0, 0);
                oB[mt] = __builtin_amdgcn_mfma_f32_16x16x16bf16_1k(vfr[mt][ks], pB.v, oB[mt], 0, 0, 0);
            }
        }
        __builtin_amdgcn_s_setprio(0);
    }
#undef STAGE
#undef STAGE1

    rowA += __shfl_xor(rowA, 16, 64);
    rowA += __shfl_xor(rowA, 32, 64);
    rowB += __shfl_xor(rowB, 16, 64);
    rowB += __shfl_xor(rowB, 32, 64);
    const float invA = 1.0f / rowA;
    const float invB = 1.0f / rowB;

#pragma unroll
    for (int mt = 0; mt < 4; ++mt) {
        bf16x4 oa, ob;
#pragma unroll
        for (int r = 0; r < 4; ++r) {
            oa[r] = (short)f2bf(oA[mt][r] * invA);
            ob[r] = (short)f2bf(oB[mt][r] * invB);
        }
        *(bf16x4*)&Y[qrowA * 1024 + h * 64 + mt * 16 + quad * 4] = oa;
        *(bf16x4*)&Y[qrowB * 1024 + h * 64 + mt * 16 + quad * 4] = ob;
    }
}

// ---------------------------------------------------------------------------
extern "C" void kernel_launch(void* const* d_in, const int* in_sizes, int n_in,
                              void* d_out, int out_size, void* d_ws, size_t ws_size,
                              hipStream_t stream) {
    const float* tgt = (const float*)d_in[0];
    const float* mem = (const float*)d_in[1];
    const float* Wq  = (const float*)d_in[2];
    const float* bq  = (const float*)d_in[3];
    const float* Wk  = (const float*)d_in[4];
    const float* bk  = (const float*)d_in[5];
    const float* Wv  = (const float*)d_in[6];
    const float* bv  = (const float*)d_in[7];
    const float* Wo  = (const float*)d_in[8];
    const float* bo  = (const float*)d_in[9];

    u16* ws = (u16*)d_ws;
    const size_t SZ = 4194304;          // elements per 4096x1024 bf16 buffer
    u16* Wt   = ws;                     // 4 x 1024x1024 bf16 (8 MB)
    u16* tgtb = ws + 4 * SZ;
    u16* memb = tgtb + SZ;
    u16* Qb   = memb + SZ;
    u16* Kb   = Qb + SZ;
    u16* Vtb  = Kb + SZ;                // 32 x 64 x 2048
    u16* Yb   = Vtb + SZ;
    float* out = (float*)d_out;

    prep<<<dim3(3072), 256, 0, stream>>>(tgt, mem, Wq, Wk, Wv, Wo, Wt, tgtb, memb);
    gemm_qkv<<<dim3(32, 8, 3), 256, 0, stream>>>(tgtb, memb, Wt, bq, bk, bv, Qb, Kb, Vtb);
    attn_kernel<<<dim3(512), 256, 0, stream>>>(Qb, Kb, Vtb, Yb);
    gemm_out<<<dim3(64, 8), 256, 0, stream>>>(Yb, Wt + 3 * (size_t)1048576, bo, out);
}